// Round 2
// baseline (161.666 us; speedup 1.0000x reference)
//
#include <hip/hip_runtime.h>
#include <math.h>

#define TAU_INV 2.0f   // 1/0.5
#define EPS 1e-8f
#define NBLK 1024      // fixed partial count; d_ws usage = 4 KB

// Grid-stride over rows. One 32-lane group per row (D=128 = 32 x float4).
// Each block plain-stores its partial sum to partials[blockIdx.x] -- no
// atomics, no memset dependence, deterministic.
__global__ __launch_bounds__(256) void contrast_partial(
    const float* __restrict__ xr, const float* __restrict__ xp,
    const float* __restrict__ xn, float* __restrict__ partials, int N)
{
    const int lane   = threadIdx.x & 31;
    const int lgrp   = threadIdx.x >> 5;          // 0..7 within block
    const int stride = NBLK * 8;                  // groups per grid pass

    float acc = 0.0f;
    for (int g = blockIdx.x * 8 + lgrp; g < N; g += stride) {
        const size_t base = (size_t)g * 128;
        const float4 r = ((const float4*)(xr + base))[lane];
        const float4 p = ((const float4*)(xp + base))[lane];
        const float4 n = ((const float4*)(xn + base))[lane];

        float s_rp = r.x*p.x + r.y*p.y + r.z*p.z + r.w*p.w;
        float s_rn = r.x*n.x + r.y*n.y + r.z*n.z + r.w*n.w;
        float s_rr = r.x*r.x + r.y*r.y + r.z*r.z + r.w*r.w;
        float s_pp = p.x*p.x + p.y*p.y + p.z*p.z + p.w*p.w;
        float s_nn = n.x*n.x + n.y*n.y + n.z*n.z + n.w*n.w;

        // Butterfly within the 32-lane group (xor masks < 32 stay inside
        // the active half-wave even if the other half exited the loop).
        #pragma unroll
        for (int off = 16; off > 0; off >>= 1) {
            s_rp += __shfl_xor(s_rp, off);
            s_rn += __shfl_xor(s_rn, off);
            s_rr += __shfl_xor(s_rr, off);
            s_pp += __shfl_xor(s_pp, off);
            s_nn += __shfl_xor(s_nn, off);
        }

        const float nr  = sqrtf(s_rr);
        const float pos = expf(s_rp / (nr * sqrtf(s_pp)) * TAU_INV);
        const float neg = expf(s_rn / (nr * sqrtf(s_nn)) * TAU_INV);
        acc += pos / (neg + EPS);   // identical value on all 32 lanes
    }

    // Per-group value is replicated across its 32 lanes; take lane 0 of each.
    __shared__ float part[8];
    if (lane == 0) part[lgrp] = acc;
    __syncthreads();
    if (threadIdx.x == 0) {
        float t = 0.0f;
        #pragma unroll
        for (int i = 0; i < 8; ++i) t += part[i];
        partials[blockIdx.x] = t;   // plain store, unconditional
    }
}

// Single block: reduce the NBLK partials (all freshly written), write -log.
__global__ __launch_bounds__(256) void contrast_final(
    const float* __restrict__ partials, float* __restrict__ out)
{
    float s = 0.0f;
    #pragma unroll
    for (int i = 0; i < NBLK / 256; ++i)
        s += partials[threadIdx.x + i * 256];

    #pragma unroll
    for (int off = 32; off > 0; off >>= 1)
        s += __shfl_xor(s, off);    // full wave64 butterfly

    __shared__ float w[4];
    if ((threadIdx.x & 63) == 0) w[threadIdx.x >> 6] = s;
    __syncthreads();
    if (threadIdx.x == 0)
        out[0] = -logf(w[0] + w[1] + w[2] + w[3]);
}

extern "C" void kernel_launch(void* const* d_in, const int* in_sizes, int n_in,
                              void* d_out, int out_size, void* d_ws, size_t ws_size,
                              hipStream_t stream) {
    const float* xr = (const float*)d_in[0];
    const float* xp = (const float*)d_in[1];
    const float* xn = (const float*)d_in[2];
    float* out      = (float*)d_out;
    float* partials = (float*)d_ws;

    const int N = in_sizes[0] / 128;    // 100000

    contrast_partial<<<NBLK, 256, 0, stream>>>(xr, xp, xn, partials, N);
    contrast_final<<<1, 256, 0, stream>>>(partials, out);
}